// Round 9
// baseline (2395.246 us; speedup 1.0000x reference)
//
#include <hip/hip_runtime.h>
#include <math.h>

#define BB   512
#define TT   256
#define HH   512
#define DIN  514
#define DOUTN 2
#define DT   0.1f
#define TH   (TT * HH)

typedef short s16x8 __attribute__((ext_vector_type(8)));
typedef float f32x4 __attribute__((ext_vector_type(4)));

__device__ __forceinline__ float retanh_f(float a) {
    float am = fminf(a, 15.0f);
    float E  = __expf(2.0f * am);
    float tp = __fdividef(E - 1.0f, E + 1.0f);
    return a > 0.0f ? tp : 0.0f;
}

__device__ __forceinline__ unsigned short f2bf(float f) {
    unsigned u = __float_as_uint(f);
    unsigned r = (u + 0x7FFFu + ((u >> 16) & 1u)) >> 16;
    return (unsigned short)r;
}

// ---------------------------------------------------------------------------
// Kernel 1a: WxT[d][j] = Wx[j][d]
// ---------------------------------------------------------------------------
__global__ __launch_bounds__(256) void transpose_wx(const float* __restrict__ Wx,
                                                    float* __restrict__ WxT) {
    int idx = blockIdx.x * 256 + threadIdx.x;
    if (idx < DIN * HH) {
        int d = idx / HH, j = idx % HH;
        WxT[idx] = Wx[j * DIN + d];
    }
}

// ---------------------------------------------------------------------------
// Kernel 1b: pack W_h into bf16 MFMA B-fragments (PROVEN rounds 6-8).
// frag f = (kc*32 + jt)*64 + lane, elem e: B[k][j]=Wh[j][k],
//   j = jt*16 + (lane&15), k = kc*32 + (lane>>4)*8 + e.
// ---------------------------------------------------------------------------
__global__ __launch_bounds__(256) void pack_wh(const float* __restrict__ Wh,
                                               unsigned short* __restrict__ Wp) {
    const int idx = blockIdx.x * 256 + threadIdx.x;   // 0..32767
    const int l  = idx & 63;
    const int jt = (idx >> 6) & 31;
    const int kc = idx >> 11;
    const int j  = jt * 16 + (l & 15);
    const int k0 = kc * 32 + (l >> 4) * 8;
    s16x8 pv;
    #pragma unroll
    for (int e = 0; e < 8; ++e) pv[e] = (short)f2bf(Wh[j * HH + k0 + e]);
    *(s16x8*)&Wp[(size_t)idx * 8] = pv;
}

// ---------------------------------------------------------------------------
// Kernel 2: x2ah = x @ WxT + b, PACKED with noise:
//   out word = (bf16(x2) << 16) | bf16(noise)   -> scan reads ONE dword per
// (b,t,j) and unpacks both. Written into the hstore region of d_out.
// ---------------------------------------------------------------------------
__global__ __launch_bounds__(256) void x2ah_kernel(const float* __restrict__ X,
                                                   const float* __restrict__ WxT,
                                                   const float* __restrict__ bias,
                                                   const float* __restrict__ noise,
                                                   unsigned int* __restrict__ outp) {
    __shared__ float xs[16][516];
    const int tid = threadIdx.x;
    const int r0  = blockIdx.x * 16;

    #pragma unroll
    for (int m = 0; m < 16; ++m) {
        const float* xr = X + (r0 + m) * DIN;
        xs[m][tid]       = xr[tid];
        xs[m][tid + 256] = xr[tid + 256];
        if (tid < 2) xs[m][512 + tid] = xr[512 + tid];
    }
    __syncthreads();

    const int j = 2 * tid;
    const float2 bv = *(const float2*)&bias[j];
    float acc[16][2];
    #pragma unroll
    for (int m = 0; m < 16; ++m) { acc[m][0] = bv.x; acc[m][1] = bv.y; }

    for (int d = 0; d < 512; d += 4) {
        const float2 w0 = *(const float2*)&WxT[(d + 0) * HH + j];
        const float2 w1 = *(const float2*)&WxT[(d + 1) * HH + j];
        const float2 w2 = *(const float2*)&WxT[(d + 2) * HH + j];
        const float2 w3 = *(const float2*)&WxT[(d + 3) * HH + j];
        #pragma unroll
        for (int m = 0; m < 16; ++m) {
            const float4 xv = *(const float4*)&xs[m][d];
            acc[m][0] += xv.x * w0.x; acc[m][1] += xv.x * w0.y;
            acc[m][0] += xv.y * w1.x; acc[m][1] += xv.y * w1.y;
            acc[m][0] += xv.z * w2.x; acc[m][1] += xv.z * w2.y;
            acc[m][0] += xv.w * w3.x; acc[m][1] += xv.w * w3.y;
        }
    }
    {
        const float2 wa = *(const float2*)&WxT[512 * HH + j];
        const float2 wb = *(const float2*)&WxT[513 * HH + j];
        #pragma unroll
        for (int m = 0; m < 16; ++m) {
            acc[m][0] += xs[m][512] * wa.x; acc[m][1] += xs[m][512] * wa.y;
            acc[m][0] += xs[m][513] * wb.x; acc[m][1] += xs[m][513] * wb.y;
        }
    }
    #pragma unroll
    for (int m = 0; m < 16; ++m) {
        const float2 nv = *(const float2*)&noise[(r0 + m) * HH + j];
        unsigned int p0 = ((unsigned)f2bf(acc[m][0]) << 16) | f2bf(nv.x);
        unsigned int p1 = ((unsigned)f2bf(acc[m][1]) << 16) | f2bf(nv.y);
        *(uint2*)&outp[(r0 + m) * HH + j] = make_uint2(p0, p1);
    }
}

// ---------------------------------------------------------------------------
// Kernel 3 (Design H3): MFMA scan, W pinned in AGPRs.
// 32 WGs x 512 thr, 1 WG/CU. Total regs/wave <= 256 (2 waves/SIMD):
//   W kc4..15 = 48 s16x8 = 192 AGPR (asm "+a" pin -> cannot be
//   rematerialized or spilled to scratch); kc0..3 in 128 KB LDS.
//   Arch VGPRs: acc 16 + ah 16 + pk 16 + temps ~16.
// Per step: 16 packed-u32 loads (issued pre-GEMM, consumed post-barrier),
// 64 MFMA, 32 ds_read_b128, epilogue, 2 barriers. Zero steady-state W traffic.
// ---------------------------------------------------------------------------
#define WDECL(KC) s16x8 wA##KC, wB##KC, wC##KC, wD##KC

#define WLOAD(KC) do { \
    wA##KC = WpW[((KC) + 4) * 2048 + 0 * 64]; \
    wB##KC = WpW[((KC) + 4) * 2048 + 1 * 64]; \
    wC##KC = WpW[((KC) + 4) * 2048 + 2 * 64]; \
    wD##KC = WpW[((KC) + 4) * 2048 + 3 * 64]; \
} while (0)

#define WPIN(KC) asm volatile("" : "+a"(wA##KC), "+a"(wB##KC), "+a"(wC##KC), "+a"(wD##KC))

#define KSTEP_REG(KC) do { \
    const s16x8 A = *(const s16x8*)&hrow[((KC) + 4) * 32]; \
    acc0 = __builtin_amdgcn_mfma_f32_16x16x32_bf16(A, wA##KC, acc0, 0, 0, 0); \
    acc1 = __builtin_amdgcn_mfma_f32_16x16x32_bf16(A, wB##KC, acc1, 0, 0, 0); \
    acc2 = __builtin_amdgcn_mfma_f32_16x16x32_bf16(A, wC##KC, acc2, 0, 0, 0); \
    acc3 = __builtin_amdgcn_mfma_f32_16x16x32_bf16(A, wD##KC, acc3, 0, 0, 0); \
} while (0)

#define KSTEP_LDS(KC) do { \
    const s16x8 A  = *(const s16x8*)&hrow[(KC) * 32]; \
    const s16x8 B0 = WlW[(KC) * 2048 + 0 * 64]; \
    const s16x8 B1 = WlW[(KC) * 2048 + 1 * 64]; \
    const s16x8 B2 = WlW[(KC) * 2048 + 2 * 64]; \
    const s16x8 B3 = WlW[(KC) * 2048 + 3 * 64]; \
    acc0 = __builtin_amdgcn_mfma_f32_16x16x32_bf16(A, B0, acc0, 0, 0, 0); \
    acc1 = __builtin_amdgcn_mfma_f32_16x16x32_bf16(A, B1, acc1, 0, 0, 0); \
    acc2 = __builtin_amdgcn_mfma_f32_16x16x32_bf16(A, B2, acc2, 0, 0, 0); \
    acc3 = __builtin_amdgcn_mfma_f32_16x16x32_bf16(A, B3, acc3, 0, 0, 0); \
} while (0)

#define PKL(N) do { \
    pk##N##_0 = hio[gb + 0 * TH + jn##N]; \
    pk##N##_1 = hio[gb + 1 * TH + jn##N]; \
    pk##N##_2 = hio[gb + 2 * TH + jn##N]; \
    pk##N##_3 = hio[gb + 3 * TH + jn##N]; \
} while (0)

#define EPI1(N, R) do { \
    const unsigned int p = pk##N##_##R; \
    const float x2 = __uint_as_float(p & 0xffff0000u); \
    const float nz = __uint_as_float(p << 16); \
    float a = ahv##N[R]; \
    a += DT * (acc##N[R] + x2 - a); \
    ahv##N[R] = a; \
    const float h = retanh_f(a) + nz; \
    hio[gb + (R) * TH + jn##N] = __float_as_uint(h); \
    hs[lg4 + (R)][jn##N] = f2bf(h); \
} while (0)

#define EPI(N) do { EPI1(N, 0); EPI1(N, 1); EPI1(N, 2); EPI1(N, 3); } while (0)

__global__ __launch_bounds__(512, 2) void scan9_kernel(const unsigned short* __restrict__ Wp,
                                                       const float* __restrict__ ah0,
                                                       unsigned int* __restrict__ hio) {
    __shared__ __align__(16) unsigned short Wl[4 * 32 * 64 * 8];  // 128 KB: kc 0..3
    __shared__ __align__(16) unsigned short hs[16][520];          // 16.25 KB

    const int tid = threadIdx.x;
    const int l   = tid & 63;
    const int w   = tid >> 6;
    const int lm  = l & 15;
    const int lg  = l >> 4;
    const int lg4 = lg * 4;
    const int b0  = blockIdx.x * 16;

    const s16x8* WpV = (const s16x8*)Wp;
    s16x8* WlV = (s16x8*)Wl;

    // one-time: kc 0..3 into LDS
    for (int idx = tid; idx < 4 * 32 * 64; idx += 512)
        WlV[idx] = WpV[idx];

    // one-time: kc 4..15 into 48 AGPR-pinned fragments
    const s16x8* WpW = WpV + (size_t)(4 * w) * 64 + l;
    WDECL(0);  WDECL(1);  WDECL(2);  WDECL(3);
    WDECL(4);  WDECL(5);  WDECL(6);  WDECL(7);
    WDECL(8);  WDECL(9);  WDECL(10); WDECL(11);
    WLOAD(0);  WLOAD(1);  WLOAD(2);  WLOAD(3);
    WLOAD(4);  WLOAD(5);  WLOAD(6);  WLOAD(7);
    WLOAD(8);  WLOAD(9);  WLOAD(10); WLOAD(11);
    WPIN(0);  WPIN(1);  WPIN(2);  WPIN(3);
    WPIN(4);  WPIN(5);  WPIN(6);  WPIN(7);
    WPIN(8);  WPIN(9);  WPIN(10); WPIN(11);

    const int jn0 = (4 * w + 0) * 16 + lm;
    const int jn1 = (4 * w + 1) * 16 + lm;
    const int jn2 = (4 * w + 2) * 16 + lm;
    const int jn3 = (4 * w + 3) * 16 + lm;

    f32x4 ahv0, ahv1, ahv2, ahv3;
    {
        const float a0 = ah0[jn0], a1 = ah0[jn1], a2 = ah0[jn2], a3 = ah0[jn3];
        ahv0 = (f32x4){a0, a0, a0, a0};
        ahv1 = (f32x4){a1, a1, a1, a1};
        ahv2 = (f32x4){a2, a2, a2, a2};
        ahv3 = (f32x4){a3, a3, a3, a3};
    }

    // init h(t=0) = retanh(ah0), same for all batch rows
    for (int idx = tid; idx < 16 * 512; idx += 512) {
        int b = idx >> 9, k = idx & 511;
        hs[b][k] = f2bf(retanh_f(ah0[k]));
    }
    __syncthreads();

    const unsigned short* hrow = &hs[lm][lg * 8];
    const s16x8* WlW = WlV + (size_t)(4 * w) * 64 + l;

    int gb = (b0 + lg4) * TH;   // + t*HH added incrementally

    for (int t = 0; t < TT; ++t) {
        // issue packed x2|noise loads (consumed after barrier 1)
        unsigned int pk0_0, pk0_1, pk0_2, pk0_3;
        unsigned int pk1_0, pk1_1, pk1_2, pk1_3;
        unsigned int pk2_0, pk2_1, pk2_2, pk2_3;
        unsigned int pk3_0, pk3_1, pk3_2, pk3_3;
        PKL(0); PKL(1); PKL(2); PKL(3);

        f32x4 acc0 = (f32x4){0.f, 0.f, 0.f, 0.f};
        f32x4 acc1 = (f32x4){0.f, 0.f, 0.f, 0.f};
        f32x4 acc2 = (f32x4){0.f, 0.f, 0.f, 0.f};
        f32x4 acc3 = (f32x4){0.f, 0.f, 0.f, 0.f};

        // interleave LDS-B steps among register-B steps (spreads LDS pressure)
        KSTEP_LDS(0);  KSTEP_REG(0);  KSTEP_REG(1);  KSTEP_REG(2);
        KSTEP_LDS(1);  KSTEP_REG(3);  KSTEP_REG(4);  KSTEP_REG(5);
        KSTEP_LDS(2);  KSTEP_REG(6);  KSTEP_REG(7);  KSTEP_REG(8);
        KSTEP_LDS(3);  KSTEP_REG(9);  KSTEP_REG(10); KSTEP_REG(11);

        __syncthreads();   // all reads of hs(t) complete

        EPI(0); EPI(1); EPI(2); EPI(3);

        gb += HH;
        __syncthreads();   // hs(t+1) complete before next step's reads
    }
}

// ---------------------------------------------------------------------------
// Kernel 4: tiny output projection (reads fp32 h written by the scan)
// ---------------------------------------------------------------------------
__global__ __launch_bounds__(256) void out_kernel(const float* __restrict__ hstore,
                                                  const float* __restrict__ Wy,
                                                  float* __restrict__ out0) {
    const int wave = threadIdx.x >> 6;
    const int lane = threadIdx.x & 63;
    const int r = blockIdx.x * 4 + wave;

    const float4* hv4 = (const float4*)&hstore[r * HH];
    float a0 = 0.0f, a1 = 0.0f;
    #pragma unroll
    for (int u = 0; u < 2; ++u) {
        const int e = u * 64 + lane;
        const float4 h  = hv4[e];
        const float4 w0 = *(const float4*)&Wy[e * 4];
        const float4 w1 = *(const float4*)&Wy[HH + e * 4];
        a0 += h.x * w0.x + h.y * w0.y + h.z * w0.z + h.w * w0.w;
        a1 += h.x * w1.x + h.y * w1.y + h.z * w1.z + h.w * w1.w;
    }
    #pragma unroll
    for (int off = 32; off > 0; off >>= 1) {
        a0 += __shfl_xor(a0, off);
        a1 += __shfl_xor(a1, off);
    }
    if (lane == 0) {
        out0[r * 2]     = a0;
        out0[r * 2 + 1] = a1;
    }
}

// ---------------------------------------------------------------------------
extern "C" void kernel_launch(void* const* d_in, const int* in_sizes, int n_in,
                              void* d_out, int out_size, void* d_ws, size_t ws_size,
                              hipStream_t stream) {
    const float* x     = (const float*)d_in[0];  // [B,T,DIN]
    const float* noise = (const float*)d_in[1];  // [B,T,H]
    const float* Wx    = (const float*)d_in[2];  // [H,DIN]
    const float* bah   = (const float*)d_in[3];  // [H]
    const float* Wh    = (const float*)d_in[4];  // [H,H]
    const float* Wy    = (const float*)d_in[5];  // [DOUT,H]
    const float* ah0   = (const float*)d_in[6];  // [H]

    float* out0   = (float*)d_out;                   // [B,T,DOUT]
    float* hstore = (float*)d_out + BB * TT * DOUTN; // [B,T,H]

    float* WxT = (float*)d_ws;                              // [DIN,H] fp32
    unsigned short* Wp = (unsigned short*)(WxT + DIN * HH); // [512*512] bf16

    transpose_wx<<<(DIN * HH + 255) / 256, 256, 0, stream>>>(Wx, WxT);
    pack_wh<<<16 * 32 * 64 / 256, 256, 0, stream>>>(Wh, Wp);
    x2ah_kernel<<<BB * TT / 16, 256, 0, stream>>>(x, WxT, bah, noise,
                                                  (unsigned int*)hstore);
    scan9_kernel<<<BB / 16, 512, 0, stream>>>(Wp, ah0, (unsigned int*)hstore);
    out_kernel<<<BB * TT / 4, 256, 0, stream>>>(hstore, Wy, out0);
}